// Round 3
// baseline (245.659 us; speedup 1.0000x reference)
//
#include <hip/hip_runtime.h>

// ---------------------------------------------------------------------------
// RelativeAttention: out = softmax(QK^T*scale + relbias + mask) V, + proj
// B=4 H=8 N=2048 C=512 hd=64.  bf16 MFMA pipeline, f32 accum.
// R3: async-stage split for K/V (issue loads 1 tile early, write LDS late),
//     bf16 bias table (LDS < 32KB -> 5 blocks/CU), s_setprio around MFMA.
// ---------------------------------------------------------------------------

typedef __attribute__((ext_vector_type(8))) short short8;   // 8 bf16 (4 VGPR)
typedef __attribute__((ext_vector_type(4))) float f32x4;    // MFMA C/D

#define SEQ   2048
#define NHEAD 8
#define NBATCH 4
#define HD    64
#define CDIM  512

__device__ __forceinline__ unsigned short f32_to_bf16_rn(float f) {
  unsigned u = __builtin_bit_cast(unsigned, f);
  u += 0x7FFFu + ((u >> 16) & 1u);
  return (unsigned short)(u >> 16);
}

// -------------------------------- f32 -> bf16 convert (vectorized) ----------
__global__ __launch_bounds__(256) void cvt_f32_bf16(const float* __restrict__ in,
                                                    ushort* __restrict__ out, int n4) {
  int i = blockIdx.x * 256 + threadIdx.x;
  const int stride = gridDim.x * 256;
  for (; i < n4; i += stride) {
    float4 v = reinterpret_cast<const float4*>(in)[i];
    ushort4 o;
    o.x = f32_to_bf16_rn(v.x);
    o.y = f32_to_bf16_rn(v.y);
    o.z = f32_to_bf16_rn(v.z);
    o.w = f32_to_bf16_rn(v.w);
    reinterpret_cast<ushort4*>(out)[i] = o;
  }
}

// -------------------------------- NT GEMM: C = A(MxK) * B(NxK)^T ------------
// 128x128 tile, 4 waves (2x2), each wave 64x64 = 4x4 frags of 16x16x32 bf16.
// MODE 0: QKV epilogue -> scatter q[b,h,n,d], k[b,h,n,d], vT[b,h,d,n] (bf16)
// MODE 1: proj epilogue -> f32 out += bias
template <int MODE>
__global__ __launch_bounds__(256) void gemm_nt(
    const ushort* __restrict__ A, const ushort* __restrict__ Bm,
    ushort* __restrict__ qo, ushort* __restrict__ ko, ushort* __restrict__ vto,
    const float* __restrict__ bias, float* __restrict__ outf) {
  const int K = 512;
  __shared__ ushort As[128 * 40];
  __shared__ ushort Bs[128 * 40];

  const int t = threadIdx.x;
  const int bn = blockIdx.x, bm = blockIdx.y;
  const int lane = t & 63, w = t >> 6;
  const int wm = w >> 1, wn = w & 1;
  const int lr = lane & 15, lq = lane >> 4;
  const int m0 = bm * 128, n0 = bn * 128;

  f32x4 acc[4][4];
#pragma unroll
  for (int i = 0; i < 4; ++i)
#pragma unroll
    for (int j = 0; j < 4; ++j) acc[i][j] = (f32x4){0.f, 0.f, 0.f, 0.f};

  for (int kt = 0; kt < K; kt += 32) {
#pragma unroll
    for (int p = 0; p < 2; ++p) {
      const int flat = p * 256 + t;
      const int row = flat >> 2, seg = flat & 3;
      *(uint4*)&As[row * 40 + seg * 8] =
          *(const uint4*)(A + (size_t)(m0 + row) * K + kt + seg * 8);
      *(uint4*)&Bs[row * 40 + seg * 8] =
          *(const uint4*)(Bm + (size_t)(n0 + row) * K + kt + seg * 8);
    }
    __syncthreads();

    short8 af[4], bf[4];
#pragma unroll
    for (int i = 0; i < 4; ++i) {
      af[i] = *(const short8*)&As[(wm * 64 + i * 16 + lr) * 40 + lq * 8];
      bf[i] = *(const short8*)&Bs[(wn * 64 + i * 16 + lr) * 40 + lq * 8];
    }
#pragma unroll
    for (int i = 0; i < 4; ++i)
#pragma unroll
      for (int j = 0; j < 4; ++j)
        acc[i][j] = __builtin_amdgcn_mfma_f32_16x16x32_bf16(af[i], bf[j], acc[i][j], 0, 0, 0);
    __syncthreads();
  }

  if constexpr (MODE == 0) {
#pragma unroll
    for (int i = 0; i < 4; ++i) {
      const int mbase = m0 + wm * 64 + i * 16 + lq * 4;  // + r
      const int bb = mbase >> 11;
      const int s0 = mbase & 2047;
#pragma unroll
      for (int j = 0; j < 4; ++j) {
        const int nb = n0 + wn * 64 + j * 16;
        const int tt = nb >> 9;
        const int hh = (nb >> 6) & 7;
        const int d0 = nb & 63;
        const int bh = bb * NHEAD + hh;
        if (tt == 2) {
          ushort4 pk;
          pk.x = f32_to_bf16_rn(acc[i][j][0]);
          pk.y = f32_to_bf16_rn(acc[i][j][1]);
          pk.z = f32_to_bf16_rn(acc[i][j][2]);
          pk.w = f32_to_bf16_rn(acc[i][j][3]);
          *(ushort4*)(vto + ((size_t)bh * HD + d0 + lr) * SEQ + s0) = pk;
        } else {
          ushort* dst = (tt == 0) ? qo : ko;
#pragma unroll
          for (int r = 0; r < 4; ++r)
            dst[((size_t)bh * SEQ + s0 + r) * HD + d0 + lr] = f32_to_bf16_rn(acc[i][j][r]);
        }
      }
    }
  } else {
#pragma unroll
    for (int i = 0; i < 4; ++i) {
#pragma unroll
      for (int j = 0; j < 4; ++j) {
        const int n = n0 + wn * 64 + j * 16 + lr;
        const float bv = bias[n];
#pragma unroll
        for (int r = 0; r < 4; ++r) {
          const int m = m0 + wm * 64 + i * 16 + lq * 4 + r;
          outf[(size_t)m * 512 + n] = acc[i][j][r] + bv;
        }
      }
    }
  }
}

// -------------------------------- fused flash attention ---------------------
// 1D grid of 1024; decode so the 8 h-blocks of each (b,qtile) land on ONE XCD
// (mask slab L2-resident, 8x reuse). 4 waves x 16 q-rows; kv tiles of 64.
// K/V staged global->reg (issued 1 tile early) -> LDS (written at loop top).
__global__ __launch_bounds__(256, 5) void attn_fused(
    const ushort* __restrict__ Q, const ushort* __restrict__ Kt,
    const ushort* __restrict__ VT, const float* __restrict__ mask,
    const float* __restrict__ Btab, ushort* __restrict__ Out) {
  __shared__ ushort Ks[64 * 72];       // 9216 B
  __shared__ ushort Vs[64 * 72];       // 9216 B
  __shared__ ushort Ps[4][16 * 68];    // 8704 B
  __shared__ ushort Bw[2112];          // 4224 B  bias*log2e, bf16

  const int flat = blockIdx.x;
  const int xcd = flat & 7;
  const int rr = flat >> 3;
  const int h = rr & 7;
  const int slot = rr >> 3;          // 0..15
  const int g = slot * 8 + xcd;      // 0..127  (b,qt) group
  const int qt = g & 31, b = g >> 5;

  const int bh = b * NHEAD + h;
  const ushort* qh = Q + (size_t)bh * SEQ * HD;
  const ushort* kh = Kt + (size_t)bh * SEQ * HD;
  const ushort* vh = VT + (size_t)bh * HD * SEQ;
  const float* mb = mask + (size_t)b * SEQ * SEQ;
  const float* bt = Btab + h * (2 * SEQ - 1);

  const int t = threadIdx.x;
  const int lane = t & 63, w = t >> 6;
  const int lr = lane & 15, lq = lane >> 4;
  const int qb0 = qt * 64;
  const int qbase = qb0 + w * 16;

  // stage bias window [qb0, qb0+2110] once, bf16, prescaled by log2(e)
  for (int i = t; i < 2111; i += 256)
    Bw[i] = f32_to_bf16_rn(bt[qb0 + i] * 1.44269504f);

  // Q fragments — loaded once
  short8 qf0, qf1;
  {
    const ushort* qp = qh + (size_t)(qbase + lr) * HD + lq * 8;
    qf0 = *(const short8*)qp;
    qf1 = *(const short8*)(qp + 32);
  }

  const float* mrow[4];
#pragma unroll
  for (int r = 0; r < 4; ++r) mrow[r] = mb + (size_t)(qbase + lq * 4 + r) * SEQ + lr;

  float l_r[4] = {0.f, 0.f, 0.f, 0.f};
  f32x4 of[4];
#pragma unroll
  for (int i = 0; i < 4; ++i) of[i] = (f32x4){0.f, 0.f, 0.f, 0.f};

  const int qrl = w * 16 + lq * 4;   // q-row within block (+r)
  const int srow = t >> 3;           // staging row 0..31
  const int sseg = t & 7;            // staging 16B segment

  // prologue: tile-0 K/V loads into regs; tile-0 mask prefetch
  uint4 kreg[2], vreg[2];
#pragma unroll
  for (int p = 0; p < 2; ++p) {
    const int row = p * 32 + srow;
    kreg[p] = *(const uint4*)(kh + (size_t)row * HD + sseg * 8);
    vreg[p] = *(const uint4*)(vh + (size_t)row * SEQ + sseg * 8);
  }
  float mnext[4][4];
#pragma unroll
  for (int f = 0; f < 4; ++f)
#pragma unroll
    for (int r = 0; r < 4; ++r) mnext[f][r] = mrow[r][f * 16];

  for (int kv0 = 0; kv0 < SEQ; kv0 += 64) {
    __syncthreads();  // all waves done reading previous tile's Ks/Vs
    {
      const int row0 = srow, row1 = 32 + srow;
      *(uint4*)&Ks[row0 * 72 + sseg * 8] = kreg[0];
      *(uint4*)&Vs[row0 * 72 + sseg * 8] = vreg[0];
      *(uint4*)&Ks[row1 * 72 + sseg * 8] = kreg[1];
      *(uint4*)&Vs[row1 * 72 + sseg * 8] = vreg[1];
    }
    __syncthreads();  // Ks/Vs ready

    const int nkv = kv0 + 64;
    if (nkv < SEQ) {  // issue next tile's loads NOW; hidden under compute
#pragma unroll
      for (int p = 0; p < 2; ++p) {
        const int row = p * 32 + srow;
        kreg[p] = *(const uint4*)(kh + (size_t)(nkv + row) * HD + sseg * 8);
        vreg[p] = *(const uint4*)(vh + (size_t)row * SEQ + nkv + sseg * 8);
      }
    }

    // S = Q K^T  (D row = q-row = lq*4+r, col = kv = f*16+lr)
    f32x4 sf[4];
    __builtin_amdgcn_s_setprio(1);
#pragma unroll
    for (int f = 0; f < 4; ++f) {
      sf[f] = (f32x4){0.f, 0.f, 0.f, 0.f};
      const ushort* kp = &Ks[(f * 16 + lr) * 72 + lq * 8];
      const short8 k0 = *(const short8*)kp;
      const short8 k1 = *(const short8*)(kp + 32);
      sf[f] = __builtin_amdgcn_mfma_f32_16x16x32_bf16(qf0, k0, sf[f], 0, 0, 0);
      sf[f] = __builtin_amdgcn_mfma_f32_16x16x32_bf16(qf1, k1, sf[f], 0, 0, 0);
    }
    __builtin_amdgcn_s_setprio(0);

    // no-max softmax: p = exp2(s*scale*log2e + bias*log2e + mask*log2e)
    float rs[4] = {0.f, 0.f, 0.f, 0.f};
#pragma unroll
    for (int f = 0; f < 4; ++f) {
      const int ib = qrl - (kv0 + f * 16 + lr) + 2047;  // + r
#pragma unroll
      for (int r = 0; r < 4; ++r) {
        const float bw = __builtin_bit_cast(float, ((unsigned)Bw[ib + r]) << 16);
        const float xs = fmaf(sf[f][r], 0.18033688f,
                              fmaf(mnext[f][r], 1.44269504f, bw));
        const float p = __builtin_amdgcn_exp2f(xs);
        rs[r] += p;
        const unsigned u = __builtin_bit_cast(unsigned, p);
        Ps[w][(lq * 4 + r) * 68 + f * 16 + lr] =
            (unsigned short)((u + 0x8000u) >> 16);
      }
    }

    if (nkv < SEQ) {  // mask prefetch for next tile (after last use of mnext)
#pragma unroll
      for (int f = 0; f < 4; ++f)
#pragma unroll
        for (int r = 0; r < 4; ++r) mnext[f][r] = mrow[r][nkv + f * 16];
    }

#pragma unroll
    for (int r = 0; r < 4; ++r) {
      float v = rs[r];
      v += __shfl_xor(v, 1);
      v += __shfl_xor(v, 2);
      v += __shfl_xor(v, 4);
      v += __shfl_xor(v, 8);
      l_r[r] += v;
    }

    // O += P V   (A-frag from Ps: row=lr, k=kv; B-frag from Vs: col=d, k=kv)
    __builtin_amdgcn_s_setprio(1);
#pragma unroll
    for (int ks = 0; ks < 2; ++ks) {
      union { uint2 u[2]; short8 s; } pu;
      const int pidx = lr * 68 + ks * 32 + lq * 8;
      pu.u[0] = *(const uint2*)&Ps[w][pidx];
      pu.u[1] = *(const uint2*)&Ps[w][pidx + 4];
#pragma unroll
      for (int hf = 0; hf < 4; ++hf) {
        const short8 vf = *(const short8*)&Vs[(hf * 16 + lr) * 72 + ks * 32 + lq * 8];
        of[hf] = __builtin_amdgcn_mfma_f32_16x16x32_bf16(pu.s, vf, of[hf], 0, 0, 0);
      }
    }
    __builtin_amdgcn_s_setprio(0);
  }

  // normalize + write bf16 [b][s][h*64+d]
#pragma unroll
  for (int r = 0; r < 4; ++r) {
    const float inv = 1.0f / l_r[r];
    const int qr = qbase + lq * 4 + r;
    ushort* op = Out + ((size_t)(b * SEQ + qr)) * CDIM + h * HD;
#pragma unroll
    for (int hf = 0; hf < 4; ++hf) op[hf * 16 + lr] = f32_to_bf16_rn(of[hf][r] * inv);
  }
}

// ---------------------------------------------------------------------------
extern "C" void kernel_launch(void* const* d_in, const int* in_sizes, int n_in,
                              void* d_out, int out_size, void* d_ws, size_t ws_size,
                              hipStream_t stream) {
  const float* x     = (const float*)d_in[0];
  const float* mask  = (const float*)d_in[1];
  const float* Wqkv  = (const float*)d_in[2];
  const float* Btab  = (const float*)d_in[3];
  const float* Wproj = (const float*)d_in[4];
  const float* bproj = (const float*)d_in[5];
  float* out = (float*)d_out;

  char* ws = (char*)d_ws;
  const size_t SZ_X   = (size_t)NBATCH * SEQ * CDIM;
  const size_t SZ_QKV = (size_t)3 * CDIM * CDIM;
  const size_t SZ_PRJ = (size_t)CDIM * CDIM;
  const size_t SZ_HD  = (size_t)NBATCH * NHEAD * SEQ * HD;

  ushort* xb    = (ushort*)ws; ws += SZ_X * 2;
  ushort* wqkvb = (ushort*)ws; ws += SZ_QKV * 2;
  ushort* wprjb = (ushort*)ws; ws += SZ_PRJ * 2;
  ushort* qb    = (ushort*)ws; ws += SZ_HD * 2;
  ushort* kb    = (ushort*)ws; ws += SZ_HD * 2;
  ushort* vtb   = (ushort*)ws; ws += SZ_HD * 2;
  ushort* aob   = (ushort*)ws; ws += SZ_X * 2;

  {
    int n4 = (int)(SZ_X / 4);
    int g = (n4 + 255) / 256; if (g > 4096) g = 4096;
    cvt_f32_bf16<<<g, 256, 0, stream>>>(x, xb, n4);
  }
  {
    int n4 = (int)(SZ_QKV / 4);
    cvt_f32_bf16<<<(n4 + 255) / 256, 256, 0, stream>>>(Wqkv, wqkvb, n4);
  }
  {
    int n4 = (int)(SZ_PRJ / 4);
    cvt_f32_bf16<<<(n4 + 255) / 256, 256, 0, stream>>>(Wproj, wprjb, n4);
  }

  // QKV: M=8192, N=1536, K=512
  gemm_nt<0><<<dim3(12, 64), 256, 0, stream>>>(xb, wqkvb, qb, kb, vtb, nullptr, nullptr);

  // fused attention (1D swizzled grid)
  attn_fused<<<dim3(1024), 256, 0, stream>>>(qb, kb, vtb, mask, Btab, aob);

  // proj: M=8192, N=512, K=512, +bias, f32 out
  gemm_nt<1><<<dim3(4, 64), 256, 0, stream>>>(aob, wprjb, nullptr, nullptr, nullptr, bproj, out);
}

// Round 4
// 244.302 us; speedup vs baseline: 1.0056x; 1.0056x over previous
//
#include <hip/hip_runtime.h>

// ---------------------------------------------------------------------------
// RelativeAttention: out = softmax(QK^T*scale + relbias + mask) V, + proj
// B=4 H=8 N=2048 C=512 hd=64.  bf16 MFMA pipeline, f32 accum.
// R4: R3 minus the __launch_bounds__(256,5) pin (it forced VGPR=48 + massive
//     scratch spills: WRITE_SIZE 8MB->375MB). Async-stage split, bf16 bias
//     LDS, setprio, XCD swizzle all retained.
// ---------------------------------------------------------------------------

typedef __attribute__((ext_vector_type(8))) short short8;   // 8 bf16 (4 VGPR)
typedef __attribute__((ext_vector_type(4))) float f32x4;    // MFMA C/D

#define SEQ   2048
#define NHEAD 8
#define NBATCH 4
#define HD    64
#define CDIM  512

__device__ __forceinline__ unsigned short f32_to_bf16_rn(float f) {
  unsigned u = __builtin_bit_cast(unsigned, f);
  u += 0x7FFFu + ((u >> 16) & 1u);
  return (unsigned short)(u >> 16);
}

// -------------------------------- f32 -> bf16 convert (vectorized) ----------
__global__ __launch_bounds__(256) void cvt_f32_bf16(const float* __restrict__ in,
                                                    ushort* __restrict__ out, int n4) {
  int i = blockIdx.x * 256 + threadIdx.x;
  const int stride = gridDim.x * 256;
  for (; i < n4; i += stride) {
    float4 v = reinterpret_cast<const float4*>(in)[i];
    ushort4 o;
    o.x = f32_to_bf16_rn(v.x);
    o.y = f32_to_bf16_rn(v.y);
    o.z = f32_to_bf16_rn(v.z);
    o.w = f32_to_bf16_rn(v.w);
    reinterpret_cast<ushort4*>(out)[i] = o;
  }
}

// -------------------------------- NT GEMM: C = A(MxK) * B(NxK)^T ------------
// 128x128 tile, 4 waves (2x2), each wave 64x64 = 4x4 frags of 16x16x32 bf16.
// MODE 0: QKV epilogue -> scatter q[b,h,n,d], k[b,h,n,d], vT[b,h,d,n] (bf16)
// MODE 1: proj epilogue -> f32 out += bias
template <int MODE>
__global__ __launch_bounds__(256) void gemm_nt(
    const ushort* __restrict__ A, const ushort* __restrict__ Bm,
    ushort* __restrict__ qo, ushort* __restrict__ ko, ushort* __restrict__ vto,
    const float* __restrict__ bias, float* __restrict__ outf) {
  const int K = 512;
  __shared__ ushort As[128 * 40];
  __shared__ ushort Bs[128 * 40];

  const int t = threadIdx.x;
  const int bn = blockIdx.x, bm = blockIdx.y;
  const int lane = t & 63, w = t >> 6;
  const int wm = w >> 1, wn = w & 1;
  const int lr = lane & 15, lq = lane >> 4;
  const int m0 = bm * 128, n0 = bn * 128;

  f32x4 acc[4][4];
#pragma unroll
  for (int i = 0; i < 4; ++i)
#pragma unroll
    for (int j = 0; j < 4; ++j) acc[i][j] = (f32x4){0.f, 0.f, 0.f, 0.f};

  for (int kt = 0; kt < K; kt += 32) {
#pragma unroll
    for (int p = 0; p < 2; ++p) {
      const int flat = p * 256 + t;
      const int row = flat >> 2, seg = flat & 3;
      *(uint4*)&As[row * 40 + seg * 8] =
          *(const uint4*)(A + (size_t)(m0 + row) * K + kt + seg * 8);
      *(uint4*)&Bs[row * 40 + seg * 8] =
          *(const uint4*)(Bm + (size_t)(n0 + row) * K + kt + seg * 8);
    }
    __syncthreads();

    short8 af[4], bf[4];
#pragma unroll
    for (int i = 0; i < 4; ++i) {
      af[i] = *(const short8*)&As[(wm * 64 + i * 16 + lr) * 40 + lq * 8];
      bf[i] = *(const short8*)&Bs[(wn * 64 + i * 16 + lr) * 40 + lq * 8];
    }
#pragma unroll
    for (int i = 0; i < 4; ++i)
#pragma unroll
      for (int j = 0; j < 4; ++j)
        acc[i][j] = __builtin_amdgcn_mfma_f32_16x16x32_bf16(af[i], bf[j], acc[i][j], 0, 0, 0);
    __syncthreads();
  }

  if constexpr (MODE == 0) {
#pragma unroll
    for (int i = 0; i < 4; ++i) {
      const int mbase = m0 + wm * 64 + i * 16 + lq * 4;  // + r
      const int bb = mbase >> 11;
      const int s0 = mbase & 2047;
#pragma unroll
      for (int j = 0; j < 4; ++j) {
        const int nb = n0 + wn * 64 + j * 16;
        const int tt = nb >> 9;
        const int hh = (nb >> 6) & 7;
        const int d0 = nb & 63;
        const int bh = bb * NHEAD + hh;
        if (tt == 2) {
          ushort4 pk;
          pk.x = f32_to_bf16_rn(acc[i][j][0]);
          pk.y = f32_to_bf16_rn(acc[i][j][1]);
          pk.z = f32_to_bf16_rn(acc[i][j][2]);
          pk.w = f32_to_bf16_rn(acc[i][j][3]);
          *(ushort4*)(vto + ((size_t)bh * HD + d0 + lr) * SEQ + s0) = pk;
        } else {
          ushort* dst = (tt == 0) ? qo : ko;
#pragma unroll
          for (int r = 0; r < 4; ++r)
            dst[((size_t)bh * SEQ + s0 + r) * HD + d0 + lr] = f32_to_bf16_rn(acc[i][j][r]);
        }
      }
    }
  } else {
#pragma unroll
    for (int i = 0; i < 4; ++i) {
#pragma unroll
      for (int j = 0; j < 4; ++j) {
        const int n = n0 + wn * 64 + j * 16 + lr;
        const float bv = bias[n];
#pragma unroll
        for (int r = 0; r < 4; ++r) {
          const int m = m0 + wm * 64 + i * 16 + lq * 4 + r;
          outf[(size_t)m * 512 + n] = acc[i][j][r] + bv;
        }
      }
    }
  }
}

// -------------------------------- fused flash attention ---------------------
// 1D grid of 1024; decode so the 8 h-blocks of each (b,qtile) land on ONE XCD
// (mask slab L2-resident, 8x reuse). 4 waves x 16 q-rows; kv tiles of 64.
// K/V staged global->reg (issued 1 tile early) -> LDS (written at loop top).
__global__ __launch_bounds__(256) void attn_fused(
    const ushort* __restrict__ Q, const ushort* __restrict__ Kt,
    const ushort* __restrict__ VT, const float* __restrict__ mask,
    const float* __restrict__ Btab, ushort* __restrict__ Out) {
  __shared__ ushort Ks[64 * 72];       // 9216 B
  __shared__ ushort Vs[64 * 72];       // 9216 B
  __shared__ ushort Ps[4][16 * 68];    // 8704 B
  __shared__ ushort Bw[2112];          // 4224 B  bias*log2e, bf16

  const int flat = blockIdx.x;
  const int xcd = flat & 7;
  const int rr = flat >> 3;
  const int h = rr & 7;
  const int slot = rr >> 3;          // 0..15
  const int g = slot * 8 + xcd;      // 0..127  (b,qt) group
  const int qt = g & 31, b = g >> 5;

  const int bh = b * NHEAD + h;
  const ushort* qh = Q + (size_t)bh * SEQ * HD;
  const ushort* kh = Kt + (size_t)bh * SEQ * HD;
  const ushort* vh = VT + (size_t)bh * HD * SEQ;
  const float* mb = mask + (size_t)b * SEQ * SEQ;
  const float* bt = Btab + h * (2 * SEQ - 1);

  const int t = threadIdx.x;
  const int lane = t & 63, w = t >> 6;
  const int lr = lane & 15, lq = lane >> 4;
  const int qb0 = qt * 64;
  const int qbase = qb0 + w * 16;

  // stage bias window [qb0, qb0+2110] once, bf16, prescaled by log2(e)
  for (int i = t; i < 2111; i += 256)
    Bw[i] = f32_to_bf16_rn(bt[qb0 + i] * 1.44269504f);

  // Q fragments — loaded once
  short8 qf0, qf1;
  {
    const ushort* qp = qh + (size_t)(qbase + lr) * HD + lq * 8;
    qf0 = *(const short8*)qp;
    qf1 = *(const short8*)(qp + 32);
  }

  const float* mrow[4];
#pragma unroll
  for (int r = 0; r < 4; ++r) mrow[r] = mb + (size_t)(qbase + lq * 4 + r) * SEQ + lr;

  float l_r[4] = {0.f, 0.f, 0.f, 0.f};
  f32x4 of[4];
#pragma unroll
  for (int i = 0; i < 4; ++i) of[i] = (f32x4){0.f, 0.f, 0.f, 0.f};

  const int qrl = w * 16 + lq * 4;   // q-row within block (+r)
  const int srow = t >> 3;           // staging row 0..31
  const int sseg = t & 7;            // staging 16B segment

  // prologue: tile-0 K/V loads into regs; tile-0 mask prefetch
  uint4 kreg[2], vreg[2];
#pragma unroll
  for (int p = 0; p < 2; ++p) {
    const int row = p * 32 + srow;
    kreg[p] = *(const uint4*)(kh + (size_t)row * HD + sseg * 8);
    vreg[p] = *(const uint4*)(vh + (size_t)row * SEQ + sseg * 8);
  }
  float mnext[4][4];
#pragma unroll
  for (int f = 0; f < 4; ++f)
#pragma unroll
    for (int r = 0; r < 4; ++r) mnext[f][r] = mrow[r][f * 16];

  for (int kv0 = 0; kv0 < SEQ; kv0 += 64) {
    __syncthreads();  // all waves done reading previous tile's Ks/Vs
    {
      const int row0 = srow, row1 = 32 + srow;
      *(uint4*)&Ks[row0 * 72 + sseg * 8] = kreg[0];
      *(uint4*)&Vs[row0 * 72 + sseg * 8] = vreg[0];
      *(uint4*)&Ks[row1 * 72 + sseg * 8] = kreg[1];
      *(uint4*)&Vs[row1 * 72 + sseg * 8] = vreg[1];
    }
    __syncthreads();  // Ks/Vs ready

    const int nkv = kv0 + 64;
    if (nkv < SEQ) {  // issue next tile's loads NOW; hidden under compute
#pragma unroll
      for (int p = 0; p < 2; ++p) {
        const int row = p * 32 + srow;
        kreg[p] = *(const uint4*)(kh + (size_t)(nkv + row) * HD + sseg * 8);
        vreg[p] = *(const uint4*)(vh + (size_t)row * SEQ + nkv + sseg * 8);
      }
    }

    // S = Q K^T  (D row = q-row = lq*4+r, col = kv = f*16+lr)
    f32x4 sf[4];
    __builtin_amdgcn_s_setprio(1);
#pragma unroll
    for (int f = 0; f < 4; ++f) {
      sf[f] = (f32x4){0.f, 0.f, 0.f, 0.f};
      const ushort* kp = &Ks[(f * 16 + lr) * 72 + lq * 8];
      const short8 k0 = *(const short8*)kp;
      const short8 k1 = *(const short8*)(kp + 32);
      sf[f] = __builtin_amdgcn_mfma_f32_16x16x32_bf16(qf0, k0, sf[f], 0, 0, 0);
      sf[f] = __builtin_amdgcn_mfma_f32_16x16x32_bf16(qf1, k1, sf[f], 0, 0, 0);
    }
    __builtin_amdgcn_s_setprio(0);

    // no-max softmax: p = exp2(s*scale*log2e + bias*log2e + mask*log2e)
    float rs[4] = {0.f, 0.f, 0.f, 0.f};
#pragma unroll
    for (int f = 0; f < 4; ++f) {
      const int ib = qrl - (kv0 + f * 16 + lr) + 2047;  // + r
#pragma unroll
      for (int r = 0; r < 4; ++r) {
        const float bw = __builtin_bit_cast(float, ((unsigned)Bw[ib + r]) << 16);
        const float xs = fmaf(sf[f][r], 0.18033688f,
                              fmaf(mnext[f][r], 1.44269504f, bw));
        const float p = __builtin_amdgcn_exp2f(xs);
        rs[r] += p;
        const unsigned u = __builtin_bit_cast(unsigned, p);
        Ps[w][(lq * 4 + r) * 68 + f * 16 + lr] =
            (unsigned short)((u + 0x8000u) >> 16);
      }
    }

    if (nkv < SEQ) {  // mask prefetch for next tile (after last use of mnext)
#pragma unroll
      for (int f = 0; f < 4; ++f)
#pragma unroll
        for (int r = 0; r < 4; ++r) mnext[f][r] = mrow[r][nkv + f * 16];
    }

#pragma unroll
    for (int r = 0; r < 4; ++r) {
      float v = rs[r];
      v += __shfl_xor(v, 1);
      v += __shfl_xor(v, 2);
      v += __shfl_xor(v, 4);
      v += __shfl_xor(v, 8);
      l_r[r] += v;
    }

    // O += P V   (A-frag from Ps: row=lr, k=kv; B-frag from Vs: col=d, k=kv)
    __builtin_amdgcn_s_setprio(1);
#pragma unroll
    for (int ks = 0; ks < 2; ++ks) {
      union { uint2 u[2]; short8 s; } pu;
      const int pidx = lr * 68 + ks * 32 + lq * 8;
      pu.u[0] = *(const uint2*)&Ps[w][pidx];
      pu.u[1] = *(const uint2*)&Ps[w][pidx + 4];
#pragma unroll
      for (int hf = 0; hf < 4; ++hf) {
        const short8 vf = *(const short8*)&Vs[(hf * 16 + lr) * 72 + ks * 32 + lq * 8];
        of[hf] = __builtin_amdgcn_mfma_f32_16x16x32_bf16(pu.s, vf, of[hf], 0, 0, 0);
      }
    }
    __builtin_amdgcn_s_setprio(0);
  }

  // normalize + write bf16 [b][s][h*64+d]
#pragma unroll
  for (int r = 0; r < 4; ++r) {
    const float inv = 1.0f / l_r[r];
    const int qr = qbase + lq * 4 + r;
    ushort* op = Out + ((size_t)(b * SEQ + qr)) * CDIM + h * HD;
#pragma unroll
    for (int hf = 0; hf < 4; ++hf) op[hf * 16 + lr] = f32_to_bf16_rn(of[hf][r] * inv);
  }
}

// ---------------------------------------------------------------------------
extern "C" void kernel_launch(void* const* d_in, const int* in_sizes, int n_in,
                              void* d_out, int out_size, void* d_ws, size_t ws_size,
                              hipStream_t stream) {
  const float* x     = (const float*)d_in[0];
  const float* mask  = (const float*)d_in[1];
  const float* Wqkv  = (const float*)d_in[2];
  const float* Btab  = (const float*)d_in[3];
  const float* Wproj = (const float*)d_in[4];
  const float* bproj = (const float*)d_in[5];
  float* out = (float*)d_out;

  char* ws = (char*)d_ws;
  const size_t SZ_X   = (size_t)NBATCH * SEQ * CDIM;
  const size_t SZ_QKV = (size_t)3 * CDIM * CDIM;
  const size_t SZ_PRJ = (size_t)CDIM * CDIM;
  const size_t SZ_HD  = (size_t)NBATCH * NHEAD * SEQ * HD;

  ushort* xb    = (ushort*)ws; ws += SZ_X * 2;
  ushort* wqkvb = (ushort*)ws; ws += SZ_QKV * 2;
  ushort* wprjb = (ushort*)ws; ws += SZ_PRJ * 2;
  ushort* qb    = (ushort*)ws; ws += SZ_HD * 2;
  ushort* kb    = (ushort*)ws; ws += SZ_HD * 2;
  ushort* vtb   = (ushort*)ws; ws += SZ_HD * 2;
  ushort* aob   = (ushort*)ws; ws += SZ_X * 2;

  {
    int n4 = (int)(SZ_X / 4);
    int g = (n4 + 255) / 256; if (g > 4096) g = 4096;
    cvt_f32_bf16<<<g, 256, 0, stream>>>(x, xb, n4);
  }
  {
    int n4 = (int)(SZ_QKV / 4);
    cvt_f32_bf16<<<(n4 + 255) / 256, 256, 0, stream>>>(Wqkv, wqkvb, n4);
  }
  {
    int n4 = (int)(SZ_PRJ / 4);
    cvt_f32_bf16<<<(n4 + 255) / 256, 256, 0, stream>>>(Wproj, wprjb, n4);
  }

  // QKV: M=8192, N=1536, K=512
  gemm_nt<0><<<dim3(12, 64), 256, 0, stream>>>(xb, wqkvb, qb, kb, vtb, nullptr, nullptr);

  // fused attention (1D swizzled grid)
  attn_fused<<<dim3(1024), 256, 0, stream>>>(qb, kb, vtb, mask, Btab, aob);

  // proj: M=8192, N=512, K=512, +bias, f32 out
  gemm_nt<1><<<dim3(4, 64), 256, 0, stream>>>(aob, wprjb, nullptr, nullptr, nullptr, bproj, out);
}

// Round 5
// 193.502 us; speedup vs baseline: 1.2695x; 1.2625x over previous
//
#include <hip/hip_runtime.h>

// ---------------------------------------------------------------------------
// RelativeAttention: out = softmax(QK^T*scale + relbias + mask) V, + proj
// B=4 H=8 N=2048 C=512 hd=64.  bf16 MFMA pipeline, f32 accum.
// R5: fix R3/R4 scratch spills — the loop-carried uint4 kreg[2]/vreg[2]
//     ARRAYS (assigned under an if, used next iteration) went to scratch
//     (rule #20): WRITE_SIZE 8MB->367MB, VGPR 56->52. Replace with named
//     scalars + unconditional clamped prefetch. T14 async-stage retained.
// ---------------------------------------------------------------------------

typedef __attribute__((ext_vector_type(8))) short short8;   // 8 bf16 (4 VGPR)
typedef __attribute__((ext_vector_type(4))) float f32x4;    // MFMA C/D

#define SEQ   2048
#define NHEAD 8
#define NBATCH 4
#define HD    64
#define CDIM  512

__device__ __forceinline__ unsigned short f32_to_bf16_rn(float f) {
  unsigned u = __builtin_bit_cast(unsigned, f);
  u += 0x7FFFu + ((u >> 16) & 1u);
  return (unsigned short)(u >> 16);
}

// -------------------------------- f32 -> bf16 convert (vectorized) ----------
__global__ __launch_bounds__(256) void cvt_f32_bf16(const float* __restrict__ in,
                                                    ushort* __restrict__ out, int n4) {
  int i = blockIdx.x * 256 + threadIdx.x;
  const int stride = gridDim.x * 256;
  for (; i < n4; i += stride) {
    float4 v = reinterpret_cast<const float4*>(in)[i];
    ushort4 o;
    o.x = f32_to_bf16_rn(v.x);
    o.y = f32_to_bf16_rn(v.y);
    o.z = f32_to_bf16_rn(v.z);
    o.w = f32_to_bf16_rn(v.w);
    reinterpret_cast<ushort4*>(out)[i] = o;
  }
}

// -------------------------------- NT GEMM: C = A(MxK) * B(NxK)^T ------------
// 128x128 tile, 4 waves (2x2), each wave 64x64 = 4x4 frags of 16x16x32 bf16.
// MODE 0: QKV epilogue -> scatter q[b,h,n,d], k[b,h,n,d], vT[b,h,d,n] (bf16)
// MODE 1: proj epilogue -> f32 out += bias
template <int MODE>
__global__ __launch_bounds__(256) void gemm_nt(
    const ushort* __restrict__ A, const ushort* __restrict__ Bm,
    ushort* __restrict__ qo, ushort* __restrict__ ko, ushort* __restrict__ vto,
    const float* __restrict__ bias, float* __restrict__ outf) {
  const int K = 512;
  __shared__ ushort As[128 * 40];
  __shared__ ushort Bs[128 * 40];

  const int t = threadIdx.x;
  const int bn = blockIdx.x, bm = blockIdx.y;
  const int lane = t & 63, w = t >> 6;
  const int wm = w >> 1, wn = w & 1;
  const int lr = lane & 15, lq = lane >> 4;
  const int m0 = bm * 128, n0 = bn * 128;

  f32x4 acc[4][4];
#pragma unroll
  for (int i = 0; i < 4; ++i)
#pragma unroll
    for (int j = 0; j < 4; ++j) acc[i][j] = (f32x4){0.f, 0.f, 0.f, 0.f};

  for (int kt = 0; kt < K; kt += 32) {
#pragma unroll
    for (int p = 0; p < 2; ++p) {
      const int flat = p * 256 + t;
      const int row = flat >> 2, seg = flat & 3;
      *(uint4*)&As[row * 40 + seg * 8] =
          *(const uint4*)(A + (size_t)(m0 + row) * K + kt + seg * 8);
      *(uint4*)&Bs[row * 40 + seg * 8] =
          *(const uint4*)(Bm + (size_t)(n0 + row) * K + kt + seg * 8);
    }
    __syncthreads();

    short8 af[4], bf[4];
#pragma unroll
    for (int i = 0; i < 4; ++i) {
      af[i] = *(const short8*)&As[(wm * 64 + i * 16 + lr) * 40 + lq * 8];
      bf[i] = *(const short8*)&Bs[(wn * 64 + i * 16 + lr) * 40 + lq * 8];
    }
#pragma unroll
    for (int i = 0; i < 4; ++i)
#pragma unroll
      for (int j = 0; j < 4; ++j)
        acc[i][j] = __builtin_amdgcn_mfma_f32_16x16x32_bf16(af[i], bf[j], acc[i][j], 0, 0, 0);
    __syncthreads();
  }

  if constexpr (MODE == 0) {
#pragma unroll
    for (int i = 0; i < 4; ++i) {
      const int mbase = m0 + wm * 64 + i * 16 + lq * 4;  // + r
      const int bb = mbase >> 11;
      const int s0 = mbase & 2047;
#pragma unroll
      for (int j = 0; j < 4; ++j) {
        const int nb = n0 + wn * 64 + j * 16;
        const int tt = nb >> 9;
        const int hh = (nb >> 6) & 7;
        const int d0 = nb & 63;
        const int bh = bb * NHEAD + hh;
        if (tt == 2) {
          ushort4 pk;
          pk.x = f32_to_bf16_rn(acc[i][j][0]);
          pk.y = f32_to_bf16_rn(acc[i][j][1]);
          pk.z = f32_to_bf16_rn(acc[i][j][2]);
          pk.w = f32_to_bf16_rn(acc[i][j][3]);
          *(ushort4*)(vto + ((size_t)bh * HD + d0 + lr) * SEQ + s0) = pk;
        } else {
          ushort* dst = (tt == 0) ? qo : ko;
#pragma unroll
          for (int r = 0; r < 4; ++r)
            dst[((size_t)bh * SEQ + s0 + r) * HD + d0 + lr] = f32_to_bf16_rn(acc[i][j][r]);
        }
      }
    }
  } else {
#pragma unroll
    for (int i = 0; i < 4; ++i) {
#pragma unroll
      for (int j = 0; j < 4; ++j) {
        const int n = n0 + wn * 64 + j * 16 + lr;
        const float bv = bias[n];
#pragma unroll
        for (int r = 0; r < 4; ++r) {
          const int m = m0 + wm * 64 + i * 16 + lq * 4 + r;
          outf[(size_t)m * 512 + n] = acc[i][j][r] + bv;
        }
      }
    }
  }
}

// -------------------------------- fused flash attention ---------------------
// 1D grid of 1024; decode so the 8 h-blocks of each (b,qtile) land on ONE XCD
// (mask slab L2-resident, 8x reuse). 4 waves x 16 q-rows; kv tiles of 64.
// K/V staged global->reg (issued 1 tile early, NAMED scalars) -> LDS at loop
// top. Prefetches are unconditional with clamped index (straight-line SSA).
__global__ __launch_bounds__(256) void attn_fused(
    const ushort* __restrict__ Q, const ushort* __restrict__ Kt,
    const ushort* __restrict__ VT, const float* __restrict__ mask,
    const float* __restrict__ Btab, ushort* __restrict__ Out) {
  __shared__ ushort Ks[64 * 72];       // 9216 B
  __shared__ ushort Vs[64 * 72];       // 9216 B
  __shared__ ushort Ps[4][16 * 68];    // 8704 B
  __shared__ ushort Bw[2112];          // 4224 B  bias*log2e, bf16

  const int flat = blockIdx.x;
  const int xcd = flat & 7;
  const int rr = flat >> 3;
  const int h = rr & 7;
  const int slot = rr >> 3;          // 0..15
  const int g = slot * 8 + xcd;      // 0..127  (b,qt) group
  const int qt = g & 31, b = g >> 5;

  const int bh = b * NHEAD + h;
  const ushort* qh = Q + (size_t)bh * SEQ * HD;
  const ushort* kh = Kt + (size_t)bh * SEQ * HD;
  const ushort* vh = VT + (size_t)bh * HD * SEQ;
  const float* mb = mask + (size_t)b * SEQ * SEQ;
  const float* bt = Btab + h * (2 * SEQ - 1);

  const int t = threadIdx.x;
  const int lane = t & 63, w = t >> 6;
  const int lr = lane & 15, lq = lane >> 4;
  const int qb0 = qt * 64;
  const int qbase = qb0 + w * 16;

  // stage bias window [qb0, qb0+2110] once, bf16, prescaled by log2(e)
  for (int i = t; i < 2111; i += 256)
    Bw[i] = f32_to_bf16_rn(bt[qb0 + i] * 1.44269504f);

  // Q fragments — loaded once
  short8 qf0, qf1;
  {
    const ushort* qp = qh + (size_t)(qbase + lr) * HD + lq * 8;
    qf0 = *(const short8*)qp;
    qf1 = *(const short8*)(qp + 32);
  }

  const float* mrow[4];
#pragma unroll
  for (int r = 0; r < 4; ++r) mrow[r] = mb + (size_t)(qbase + lq * 4 + r) * SEQ + lr;

  float l_r[4] = {0.f, 0.f, 0.f, 0.f};
  f32x4 of[4];
#pragma unroll
  for (int i = 0; i < 4; ++i) of[i] = (f32x4){0.f, 0.f, 0.f, 0.f};

  const int qrl = w * 16 + lq * 4;   // q-row within block (+r)
  const int srow = t >> 3;           // staging row 0..31
  const int sseg = t & 7;            // staging 16B segment

  // per-thread staging source pointers (row/segment fixed per thread)
  const ushort* kp0 = kh + (size_t)srow * HD + sseg * 8;         // +kv0*HD
  const ushort* kp1 = kh + (size_t)(32 + srow) * HD + sseg * 8;
  const ushort* vp0 = vh + (size_t)srow * SEQ + sseg * 8;        // +kv0
  const ushort* vp1 = vh + (size_t)(32 + srow) * SEQ + sseg * 8;

  // prologue: tile-0 K/V loads into NAMED regs; tile-0 mask prefetch
  uint4 kr0 = *(const uint4*)kp0;
  uint4 kr1 = *(const uint4*)kp1;
  uint4 vr0 = *(const uint4*)vp0;
  uint4 vr1 = *(const uint4*)vp1;
  float mnext[4][4];
#pragma unroll
  for (int f = 0; f < 4; ++f)
#pragma unroll
    for (int r = 0; r < 4; ++r) mnext[f][r] = mrow[r][f * 16];

  for (int kv0 = 0; kv0 < SEQ; kv0 += 64) {
    __syncthreads();  // all waves done reading previous tile's Ks/Vs
    *(uint4*)&Ks[srow * 72 + sseg * 8] = kr0;
    *(uint4*)&Ks[(32 + srow) * 72 + sseg * 8] = kr1;
    *(uint4*)&Vs[srow * 72 + sseg * 8] = vr0;
    *(uint4*)&Vs[(32 + srow) * 72 + sseg * 8] = vr1;
    __syncthreads();  // Ks/Vs ready

    // next-tile index, clamped (last tile re-loads tile 0; discarded)
    const int nkv = (kv0 + 64 < SEQ) ? (kv0 + 64) : 0;
    kr0 = *(const uint4*)(kp0 + (size_t)nkv * HD);
    kr1 = *(const uint4*)(kp1 + (size_t)nkv * HD);
    vr0 = *(const uint4*)(vp0 + nkv);
    vr1 = *(const uint4*)(vp1 + nkv);

    // S = Q K^T  (D row = q-row = lq*4+r, col = kv = f*16+lr)
    f32x4 sf[4];
    __builtin_amdgcn_s_setprio(1);
#pragma unroll
    for (int f = 0; f < 4; ++f) {
      sf[f] = (f32x4){0.f, 0.f, 0.f, 0.f};
      const ushort* kp = &Ks[(f * 16 + lr) * 72 + lq * 8];
      const short8 k0 = *(const short8*)kp;
      const short8 k1 = *(const short8*)(kp + 32);
      sf[f] = __builtin_amdgcn_mfma_f32_16x16x32_bf16(qf0, k0, sf[f], 0, 0, 0);
      sf[f] = __builtin_amdgcn_mfma_f32_16x16x32_bf16(qf1, k1, sf[f], 0, 0, 0);
    }
    __builtin_amdgcn_s_setprio(0);

    // no-max softmax: p = exp2(s*scale*log2e + bias*log2e + mask*log2e)
    float rs[4] = {0.f, 0.f, 0.f, 0.f};
#pragma unroll
    for (int f = 0; f < 4; ++f) {
      const int ib = qrl - (kv0 + f * 16 + lr) + 2047;  // + r
#pragma unroll
      for (int r = 0; r < 4; ++r) {
        const float bw = __builtin_bit_cast(float, ((unsigned)Bw[ib + r]) << 16);
        const float xs = fmaf(sf[f][r], 0.18033688f,
                              fmaf(mnext[f][r], 1.44269504f, bw));
        const float p = __builtin_amdgcn_exp2f(xs);
        rs[r] += p;
        const unsigned u = __builtin_bit_cast(unsigned, p);
        Ps[w][(lq * 4 + r) * 68 + f * 16 + lr] =
            (unsigned short)((u + 0x8000u) >> 16);
      }
    }

    // mask prefetch for next tile (after last use of mnext), clamped
#pragma unroll
    for (int f = 0; f < 4; ++f)
#pragma unroll
      for (int r = 0; r < 4; ++r) mnext[f][r] = mrow[r][nkv + f * 16];

#pragma unroll
    for (int r = 0; r < 4; ++r) {
      float v = rs[r];
      v += __shfl_xor(v, 1);
      v += __shfl_xor(v, 2);
      v += __shfl_xor(v, 4);
      v += __shfl_xor(v, 8);
      l_r[r] += v;
    }

    // O += P V   (A-frag from Ps: row=lr, k=kv; B-frag from Vs: col=d, k=kv)
    __builtin_amdgcn_s_setprio(1);
#pragma unroll
    for (int ks = 0; ks < 2; ++ks) {
      union { uint2 u[2]; short8 s; } pu;
      const int pidx = lr * 68 + ks * 32 + lq * 8;
      pu.u[0] = *(const uint2*)&Ps[w][pidx];
      pu.u[1] = *(const uint2*)&Ps[w][pidx + 4];
#pragma unroll
      for (int hf = 0; hf < 4; ++hf) {
        const short8 vf = *(const short8*)&Vs[(hf * 16 + lr) * 72 + ks * 32 + lq * 8];
        of[hf] = __builtin_amdgcn_mfma_f32_16x16x32_bf16(pu.s, vf, of[hf], 0, 0, 0);
      }
    }
    __builtin_amdgcn_s_setprio(0);
  }

  // normalize + write bf16 [b][s][h*64+d]
#pragma unroll
  for (int r = 0; r < 4; ++r) {
    const float inv = 1.0f / l_r[r];
    const int qr = qbase + lq * 4 + r;
    ushort* op = Out + ((size_t)(b * SEQ + qr)) * CDIM + h * HD;
#pragma unroll
    for (int hf = 0; hf < 4; ++hf) op[hf * 16 + lr] = f32_to_bf16_rn(of[hf][r] * inv);
  }
}

// ---------------------------------------------------------------------------
extern "C" void kernel_launch(void* const* d_in, const int* in_sizes, int n_in,
                              void* d_out, int out_size, void* d_ws, size_t ws_size,
                              hipStream_t stream) {
  const float* x     = (const float*)d_in[0];
  const float* mask  = (const float*)d_in[1];
  const float* Wqkv  = (const float*)d_in[2];
  const float* Btab  = (const float*)d_in[3];
  const float* Wproj = (const float*)d_in[4];
  const float* bproj = (const float*)d_in[5];
  float* out = (float*)d_out;

  char* ws = (char*)d_ws;
  const size_t SZ_X   = (size_t)NBATCH * SEQ * CDIM;
  const size_t SZ_QKV = (size_t)3 * CDIM * CDIM;
  const size_t SZ_PRJ = (size_t)CDIM * CDIM;
  const size_t SZ_HD  = (size_t)NBATCH * NHEAD * SEQ * HD;

  ushort* xb    = (ushort*)ws; ws += SZ_X * 2;
  ushort* wqkvb = (ushort*)ws; ws += SZ_QKV * 2;
  ushort* wprjb = (ushort*)ws; ws += SZ_PRJ * 2;
  ushort* qb    = (ushort*)ws; ws += SZ_HD * 2;
  ushort* kb    = (ushort*)ws; ws += SZ_HD * 2;
  ushort* vtb   = (ushort*)ws; ws += SZ_HD * 2;
  ushort* aob   = (ushort*)ws; ws += SZ_X * 2;

  {
    int n4 = (int)(SZ_X / 4);
    int g = (n4 + 255) / 256; if (g > 4096) g = 4096;
    cvt_f32_bf16<<<g, 256, 0, stream>>>(x, xb, n4);
  }
  {
    int n4 = (int)(SZ_QKV / 4);
    cvt_f32_bf16<<<(n4 + 255) / 256, 256, 0, stream>>>(Wqkv, wqkvb, n4);
  }
  {
    int n4 = (int)(SZ_PRJ / 4);
    cvt_f32_bf16<<<(n4 + 255) / 256, 256, 0, stream>>>(Wproj, wprjb, n4);
  }

  // QKV: M=8192, N=1536, K=512
  gemm_nt<0><<<dim3(12, 64), 256, 0, stream>>>(xb, wqkvb, qb, kb, vtb, nullptr, nullptr);

  // fused attention (1D swizzled grid)
  attn_fused<<<dim3(1024), 256, 0, stream>>>(qb, kb, vtb, mask, Btab, aob);

  // proj: M=8192, N=512, K=512, +bias, f32 out
  gemm_nt<1><<<dim3(4, 64), 256, 0, stream>>>(aob, wprjb, nullptr, nullptr, nullptr, bproj, out);
}

// Round 6
// 176.217 us; speedup vs baseline: 1.3941x; 1.0981x over previous
//
#include <hip/hip_runtime.h>

// ---------------------------------------------------------------------------
// RelativeAttention: out = softmax(QK^T*scale + relbias + mask) V, + proj
// B=4 H=8 N=2048 C=512 hd=64.  bf16 MFMA pipeline, f32 accum.
// R6: (1) l-reduction hoisted OUT of the kv loop — no-max softmax makes l a
//     plain sum, so per-lane partials accumulate in-loop and ONE shfl-reduce
//     runs at the end (removes 512 ds_bpermute from the critical path);
//     (2) setprio removed (m190: hurts lockstep barrier-synced multi-wave
//     blocks — ours is exactly that). Rest identical to R5.
// ---------------------------------------------------------------------------

typedef __attribute__((ext_vector_type(8))) short short8;   // 8 bf16 (4 VGPR)
typedef __attribute__((ext_vector_type(4))) float f32x4;    // MFMA C/D

#define SEQ   2048
#define NHEAD 8
#define NBATCH 4
#define HD    64
#define CDIM  512

__device__ __forceinline__ unsigned short f32_to_bf16_rn(float f) {
  unsigned u = __builtin_bit_cast(unsigned, f);
  u += 0x7FFFu + ((u >> 16) & 1u);
  return (unsigned short)(u >> 16);
}

// -------------------------------- f32 -> bf16 convert (vectorized) ----------
__global__ __launch_bounds__(256) void cvt_f32_bf16(const float* __restrict__ in,
                                                    ushort* __restrict__ out, int n4) {
  int i = blockIdx.x * 256 + threadIdx.x;
  const int stride = gridDim.x * 256;
  for (; i < n4; i += stride) {
    float4 v = reinterpret_cast<const float4*>(in)[i];
    ushort4 o;
    o.x = f32_to_bf16_rn(v.x);
    o.y = f32_to_bf16_rn(v.y);
    o.z = f32_to_bf16_rn(v.z);
    o.w = f32_to_bf16_rn(v.w);
    reinterpret_cast<ushort4*>(out)[i] = o;
  }
}

// -------------------------------- NT GEMM: C = A(MxK) * B(NxK)^T ------------
// 128x128 tile, 4 waves (2x2), each wave 64x64 = 4x4 frags of 16x16x32 bf16.
// MODE 0: QKV epilogue -> scatter q[b,h,n,d], k[b,h,n,d], vT[b,h,d,n] (bf16)
// MODE 1: proj epilogue -> f32 out += bias
template <int MODE>
__global__ __launch_bounds__(256) void gemm_nt(
    const ushort* __restrict__ A, const ushort* __restrict__ Bm,
    ushort* __restrict__ qo, ushort* __restrict__ ko, ushort* __restrict__ vto,
    const float* __restrict__ bias, float* __restrict__ outf) {
  const int K = 512;
  __shared__ ushort As[128 * 40];
  __shared__ ushort Bs[128 * 40];

  const int t = threadIdx.x;
  const int bn = blockIdx.x, bm = blockIdx.y;
  const int lane = t & 63, w = t >> 6;
  const int wm = w >> 1, wn = w & 1;
  const int lr = lane & 15, lq = lane >> 4;
  const int m0 = bm * 128, n0 = bn * 128;

  f32x4 acc[4][4];
#pragma unroll
  for (int i = 0; i < 4; ++i)
#pragma unroll
    for (int j = 0; j < 4; ++j) acc[i][j] = (f32x4){0.f, 0.f, 0.f, 0.f};

  for (int kt = 0; kt < K; kt += 32) {
#pragma unroll
    for (int p = 0; p < 2; ++p) {
      const int flat = p * 256 + t;
      const int row = flat >> 2, seg = flat & 3;
      *(uint4*)&As[row * 40 + seg * 8] =
          *(const uint4*)(A + (size_t)(m0 + row) * K + kt + seg * 8);
      *(uint4*)&Bs[row * 40 + seg * 8] =
          *(const uint4*)(Bm + (size_t)(n0 + row) * K + kt + seg * 8);
    }
    __syncthreads();

    short8 af[4], bf[4];
#pragma unroll
    for (int i = 0; i < 4; ++i) {
      af[i] = *(const short8*)&As[(wm * 64 + i * 16 + lr) * 40 + lq * 8];
      bf[i] = *(const short8*)&Bs[(wn * 64 + i * 16 + lr) * 40 + lq * 8];
    }
#pragma unroll
    for (int i = 0; i < 4; ++i)
#pragma unroll
      for (int j = 0; j < 4; ++j)
        acc[i][j] = __builtin_amdgcn_mfma_f32_16x16x32_bf16(af[i], bf[j], acc[i][j], 0, 0, 0);
    __syncthreads();
  }

  if constexpr (MODE == 0) {
#pragma unroll
    for (int i = 0; i < 4; ++i) {
      const int mbase = m0 + wm * 64 + i * 16 + lq * 4;  // + r
      const int bb = mbase >> 11;
      const int s0 = mbase & 2047;
#pragma unroll
      for (int j = 0; j < 4; ++j) {
        const int nb = n0 + wn * 64 + j * 16;
        const int tt = nb >> 9;
        const int hh = (nb >> 6) & 7;
        const int d0 = nb & 63;
        const int bh = bb * NHEAD + hh;
        if (tt == 2) {
          ushort4 pk;
          pk.x = f32_to_bf16_rn(acc[i][j][0]);
          pk.y = f32_to_bf16_rn(acc[i][j][1]);
          pk.z = f32_to_bf16_rn(acc[i][j][2]);
          pk.w = f32_to_bf16_rn(acc[i][j][3]);
          *(ushort4*)(vto + ((size_t)bh * HD + d0 + lr) * SEQ + s0) = pk;
        } else {
          ushort* dst = (tt == 0) ? qo : ko;
#pragma unroll
          for (int r = 0; r < 4; ++r)
            dst[((size_t)bh * SEQ + s0 + r) * HD + d0 + lr] = f32_to_bf16_rn(acc[i][j][r]);
        }
      }
    }
  } else {
#pragma unroll
    for (int i = 0; i < 4; ++i) {
#pragma unroll
      for (int j = 0; j < 4; ++j) {
        const int n = n0 + wn * 64 + j * 16 + lr;
        const float bv = bias[n];
#pragma unroll
        for (int r = 0; r < 4; ++r) {
          const int m = m0 + wm * 64 + i * 16 + lq * 4 + r;
          outf[(size_t)m * 512 + n] = acc[i][j][r] + bv;
        }
      }
    }
  }
}

// -------------------------------- fused flash attention ---------------------
// 1D grid of 1024; decode so the 8 h-blocks of each (b,qtile) land on ONE XCD
// (mask slab L2-resident, 8x reuse). 4 waves x 16 q-rows; kv tiles of 64.
// K/V staged global->reg (issued 1 tile early, NAMED scalars) -> LDS at loop
// top. No-max softmax => l is a plain sum; reduced across lanes ONCE at end.
__global__ __launch_bounds__(256) void attn_fused(
    const ushort* __restrict__ Q, const ushort* __restrict__ Kt,
    const ushort* __restrict__ VT, const float* __restrict__ mask,
    const float* __restrict__ Btab, ushort* __restrict__ Out) {
  __shared__ ushort Ks[64 * 72];       // 9216 B
  __shared__ ushort Vs[64 * 72];       // 9216 B
  __shared__ ushort Ps[4][16 * 68];    // 8704 B
  __shared__ ushort Bw[2112];          // 4224 B  bias*log2e, bf16

  const int flat = blockIdx.x;
  const int xcd = flat & 7;
  const int rr = flat >> 3;
  const int h = rr & 7;
  const int slot = rr >> 3;          // 0..15
  const int g = slot * 8 + xcd;      // 0..127  (b,qt) group
  const int qt = g & 31, b = g >> 5;

  const int bh = b * NHEAD + h;
  const ushort* qh = Q + (size_t)bh * SEQ * HD;
  const ushort* kh = Kt + (size_t)bh * SEQ * HD;
  const ushort* vh = VT + (size_t)bh * HD * SEQ;
  const float* mb = mask + (size_t)b * SEQ * SEQ;
  const float* bt = Btab + h * (2 * SEQ - 1);

  const int t = threadIdx.x;
  const int lane = t & 63, w = t >> 6;
  const int lr = lane & 15, lq = lane >> 4;
  const int qb0 = qt * 64;
  const int qbase = qb0 + w * 16;

  // stage bias window [qb0, qb0+2110] once, bf16, prescaled by log2(e)
  for (int i = t; i < 2111; i += 256)
    Bw[i] = f32_to_bf16_rn(bt[qb0 + i] * 1.44269504f);

  // Q fragments — loaded once
  short8 qf0, qf1;
  {
    const ushort* qp = qh + (size_t)(qbase + lr) * HD + lq * 8;
    qf0 = *(const short8*)qp;
    qf1 = *(const short8*)(qp + 32);
  }

  const float* mrow[4];
#pragma unroll
  for (int r = 0; r < 4; ++r) mrow[r] = mb + (size_t)(qbase + lq * 4 + r) * SEQ + lr;

  float l_r[4] = {0.f, 0.f, 0.f, 0.f};   // per-lane partial sums (16 kv slots)
  f32x4 of[4];
#pragma unroll
  for (int i = 0; i < 4; ++i) of[i] = (f32x4){0.f, 0.f, 0.f, 0.f};

  const int qrl = w * 16 + lq * 4;   // q-row within block (+r)
  const int srow = t >> 3;           // staging row 0..31
  const int sseg = t & 7;            // staging 16B segment

  // per-thread staging source pointers (row/segment fixed per thread)
  const ushort* kp0 = kh + (size_t)srow * HD + sseg * 8;         // +kv0*HD
  const ushort* kp1 = kh + (size_t)(32 + srow) * HD + sseg * 8;
  const ushort* vp0 = vh + (size_t)srow * SEQ + sseg * 8;        // +kv0
  const ushort* vp1 = vh + (size_t)(32 + srow) * SEQ + sseg * 8;

  // prologue: tile-0 K/V loads into NAMED regs; tile-0 mask prefetch
  uint4 kr0 = *(const uint4*)kp0;
  uint4 kr1 = *(const uint4*)kp1;
  uint4 vr0 = *(const uint4*)vp0;
  uint4 vr1 = *(const uint4*)vp1;
  float mnext[4][4];
#pragma unroll
  for (int f = 0; f < 4; ++f)
#pragma unroll
    for (int r = 0; r < 4; ++r) mnext[f][r] = mrow[r][f * 16];

  for (int kv0 = 0; kv0 < SEQ; kv0 += 64) {
    __syncthreads();  // all waves done reading previous tile's Ks/Vs
    *(uint4*)&Ks[srow * 72 + sseg * 8] = kr0;
    *(uint4*)&Ks[(32 + srow) * 72 + sseg * 8] = kr1;
    *(uint4*)&Vs[srow * 72 + sseg * 8] = vr0;
    *(uint4*)&Vs[(32 + srow) * 72 + sseg * 8] = vr1;
    __syncthreads();  // Ks/Vs ready

    // next-tile index, clamped (last tile re-loads tile 0; discarded)
    const int nkv = (kv0 + 64 < SEQ) ? (kv0 + 64) : 0;
    kr0 = *(const uint4*)(kp0 + (size_t)nkv * HD);
    kr1 = *(const uint4*)(kp1 + (size_t)nkv * HD);
    vr0 = *(const uint4*)(vp0 + nkv);
    vr1 = *(const uint4*)(vp1 + nkv);

    // S = Q K^T  (D row = q-row = lq*4+r, col = kv = f*16+lr)
    f32x4 sf[4];
#pragma unroll
    for (int f = 0; f < 4; ++f) {
      sf[f] = (f32x4){0.f, 0.f, 0.f, 0.f};
      const ushort* kp = &Ks[(f * 16 + lr) * 72 + lq * 8];
      const short8 k0 = *(const short8*)kp;
      const short8 k1 = *(const short8*)(kp + 32);
      sf[f] = __builtin_amdgcn_mfma_f32_16x16x32_bf16(qf0, k0, sf[f], 0, 0, 0);
      sf[f] = __builtin_amdgcn_mfma_f32_16x16x32_bf16(qf1, k1, sf[f], 0, 0, 0);
    }

    // no-max softmax: p = exp2(s*scale*log2e + bias*log2e + mask*log2e)
    // l accumulates PER-LANE; cross-lane reduce deferred to after the loop.
#pragma unroll
    for (int f = 0; f < 4; ++f) {
      const int ib = qrl - (kv0 + f * 16 + lr) + 2047;  // + r
#pragma unroll
      for (int r = 0; r < 4; ++r) {
        const float bw = __builtin_bit_cast(float, ((unsigned)Bw[ib + r]) << 16);
        const float xs = fmaf(sf[f][r], 0.18033688f,
                              fmaf(mnext[f][r], 1.44269504f, bw));
        const float p = __builtin_amdgcn_exp2f(xs);
        l_r[r] += p;
        const unsigned u = __builtin_bit_cast(unsigned, p);
        Ps[w][(lq * 4 + r) * 68 + f * 16 + lr] =
            (unsigned short)((u + 0x8000u) >> 16);
      }
    }

    // mask prefetch for next tile (after last use of mnext), clamped
#pragma unroll
    for (int f = 0; f < 4; ++f)
#pragma unroll
      for (int r = 0; r < 4; ++r) mnext[f][r] = mrow[r][nkv + f * 16];

    // O += P V   (A-frag from Ps: row=lr, k=kv; B-frag from Vs: col=d, k=kv)
#pragma unroll
    for (int ks = 0; ks < 2; ++ks) {
      union { uint2 u[2]; short8 s; } pu;
      const int pidx = lr * 68 + ks * 32 + lq * 8;
      pu.u[0] = *(const uint2*)&Ps[w][pidx];
      pu.u[1] = *(const uint2*)&Ps[w][pidx + 4];
#pragma unroll
      for (int hf = 0; hf < 4; ++hf) {
        const short8 vf = *(const short8*)&Vs[(hf * 16 + lr) * 72 + ks * 32 + lq * 8];
        of[hf] = __builtin_amdgcn_mfma_f32_16x16x32_bf16(pu.s, vf, of[hf], 0, 0, 0);
      }
    }
  }

  // single cross-lane l reduction (16-lane groups), then normalize + write
#pragma unroll
  for (int r = 0; r < 4; ++r) {
    float v = l_r[r];
    v += __shfl_xor(v, 1);
    v += __shfl_xor(v, 2);
    v += __shfl_xor(v, 4);
    v += __shfl_xor(v, 8);
    l_r[r] = v;
  }
#pragma unroll
  for (int r = 0; r < 4; ++r) {
    const float inv = 1.0f / l_r[r];
    const int qr = qbase + lq * 4 + r;
    ushort* op = Out + ((size_t)(b * SEQ + qr)) * CDIM + h * HD;
#pragma unroll
    for (int hf = 0; hf < 4; ++hf) op[hf * 16 + lr] = f32_to_bf16_rn(of[hf][r] * inv);
  }
}

// ---------------------------------------------------------------------------
extern "C" void kernel_launch(void* const* d_in, const int* in_sizes, int n_in,
                              void* d_out, int out_size, void* d_ws, size_t ws_size,
                              hipStream_t stream) {
  const float* x     = (const float*)d_in[0];
  const float* mask  = (const float*)d_in[1];
  const float* Wqkv  = (const float*)d_in[2];
  const float* Btab  = (const float*)d_in[3];
  const float* Wproj = (const float*)d_in[4];
  const float* bproj = (const float*)d_in[5];
  float* out = (float*)d_out;

  char* ws = (char*)d_ws;
  const size_t SZ_X   = (size_t)NBATCH * SEQ * CDIM;
  const size_t SZ_QKV = (size_t)3 * CDIM * CDIM;
  const size_t SZ_PRJ = (size_t)CDIM * CDIM;
  const size_t SZ_HD  = (size_t)NBATCH * NHEAD * SEQ * HD;

  ushort* xb    = (ushort*)ws; ws += SZ_X * 2;
  ushort* wqkvb = (ushort*)ws; ws += SZ_QKV * 2;
  ushort* wprjb = (ushort*)ws; ws += SZ_PRJ * 2;
  ushort* qb    = (ushort*)ws; ws += SZ_HD * 2;
  ushort* kb    = (ushort*)ws; ws += SZ_HD * 2;
  ushort* vtb   = (ushort*)ws; ws += SZ_HD * 2;
  ushort* aob   = (ushort*)ws; ws += SZ_X * 2;

  {
    int n4 = (int)(SZ_X / 4);
    int g = (n4 + 255) / 256; if (g > 4096) g = 4096;
    cvt_f32_bf16<<<g, 256, 0, stream>>>(x, xb, n4);
  }
  {
    int n4 = (int)(SZ_QKV / 4);
    cvt_f32_bf16<<<(n4 + 255) / 256, 256, 0, stream>>>(Wqkv, wqkvb, n4);
  }
  {
    int n4 = (int)(SZ_PRJ / 4);
    cvt_f32_bf16<<<(n4 + 255) / 256, 256, 0, stream>>>(Wproj, wprjb, n4);
  }

  // QKV: M=8192, N=1536, K=512
  gemm_nt<0><<<dim3(12, 64), 256, 0, stream>>>(xb, wqkvb, qb, kb, vtb, nullptr, nullptr);

  // fused attention (1D swizzled grid)
  attn_fused<<<dim3(1024), 256, 0, stream>>>(qb, kb, vtb, mask, Btab, aob);

  // proj: M=8192, N=512, K=512, +bias, f32 out
  gemm_nt<1><<<dim3(4, 64), 256, 0, stream>>>(aob, wprjb, nullptr, nullptr, nullptr, bproj, out);
}

// Round 7
// 142.923 us; speedup vs baseline: 1.7188x; 1.2330x over previous
//
#include <hip/hip_runtime.h>

// ---------------------------------------------------------------------------
// RelativeAttention: out = softmax(QK^T*scale + relbias + mask) V, + proj
// B=4 H=8 N=2048 C=512 hd=64.  bf16 MFMA pipeline, f32 accum.
// R7: amortize per-tile overheads — 32 q-rows per wave (two 16-row groups),
//     128-thread blocks (2 waves), K-frags and V-frags read ONCE per wave
//     for both groups (LDS read/q-row halves), 5 blocks/CU (LDS 31.4KB).
//     Staging issued after SM_B to keep VGPR peak under the 3-wave/SIMD cap.
// ---------------------------------------------------------------------------

typedef __attribute__((ext_vector_type(8))) short short8;   // 8 bf16 (4 VGPR)
typedef __attribute__((ext_vector_type(4))) float f32x4;    // MFMA C/D

#define SEQ   2048
#define NHEAD 8
#define NBATCH 4
#define HD    64
#define CDIM  512

__device__ __forceinline__ unsigned short f32_to_bf16_rn(float f) {
  unsigned u = __builtin_bit_cast(unsigned, f);
  u += 0x7FFFu + ((u >> 16) & 1u);
  return (unsigned short)(u >> 16);
}

// -------------------------------- f32 -> bf16 convert (vectorized) ----------
__global__ __launch_bounds__(256) void cvt_f32_bf16(const float* __restrict__ in,
                                                    ushort* __restrict__ out, int n4) {
  int i = blockIdx.x * 256 + threadIdx.x;
  const int stride = gridDim.x * 256;
  for (; i < n4; i += stride) {
    float4 v = reinterpret_cast<const float4*>(in)[i];
    ushort4 o;
    o.x = f32_to_bf16_rn(v.x);
    o.y = f32_to_bf16_rn(v.y);
    o.z = f32_to_bf16_rn(v.z);
    o.w = f32_to_bf16_rn(v.w);
    reinterpret_cast<ushort4*>(out)[i] = o;
  }
}

// -------------------------------- NT GEMM: C = A(MxK) * B(NxK)^T ------------
// 128x128 tile, 4 waves (2x2), each wave 64x64 = 4x4 frags of 16x16x32 bf16.
// MODE 0: QKV epilogue -> scatter q[b,h,n,d], k[b,h,n,d], vT[b,h,d,n] (bf16)
// MODE 1: proj epilogue -> f32 out += bias
template <int MODE>
__global__ __launch_bounds__(256) void gemm_nt(
    const ushort* __restrict__ A, const ushort* __restrict__ Bm,
    ushort* __restrict__ qo, ushort* __restrict__ ko, ushort* __restrict__ vto,
    const float* __restrict__ bias, float* __restrict__ outf) {
  const int K = 512;
  __shared__ ushort As[128 * 40];
  __shared__ ushort Bs[128 * 40];

  const int t = threadIdx.x;
  const int bn = blockIdx.x, bm = blockIdx.y;
  const int lane = t & 63, w = t >> 6;
  const int wm = w >> 1, wn = w & 1;
  const int lr = lane & 15, lq = lane >> 4;
  const int m0 = bm * 128, n0 = bn * 128;

  f32x4 acc[4][4];
#pragma unroll
  for (int i = 0; i < 4; ++i)
#pragma unroll
    for (int j = 0; j < 4; ++j) acc[i][j] = (f32x4){0.f, 0.f, 0.f, 0.f};

  for (int kt = 0; kt < K; kt += 32) {
#pragma unroll
    for (int p = 0; p < 2; ++p) {
      const int flat = p * 256 + t;
      const int row = flat >> 2, seg = flat & 3;
      *(uint4*)&As[row * 40 + seg * 8] =
          *(const uint4*)(A + (size_t)(m0 + row) * K + kt + seg * 8);
      *(uint4*)&Bs[row * 40 + seg * 8] =
          *(const uint4*)(Bm + (size_t)(n0 + row) * K + kt + seg * 8);
    }
    __syncthreads();

    short8 af[4], bf[4];
#pragma unroll
    for (int i = 0; i < 4; ++i) {
      af[i] = *(const short8*)&As[(wm * 64 + i * 16 + lr) * 40 + lq * 8];
      bf[i] = *(const short8*)&Bs[(wn * 64 + i * 16 + lr) * 40 + lq * 8];
    }
#pragma unroll
    for (int i = 0; i < 4; ++i)
#pragma unroll
      for (int j = 0; j < 4; ++j)
        acc[i][j] = __builtin_amdgcn_mfma_f32_16x16x32_bf16(af[i], bf[j], acc[i][j], 0, 0, 0);
    __syncthreads();
  }

  if constexpr (MODE == 0) {
#pragma unroll
    for (int i = 0; i < 4; ++i) {
      const int mbase = m0 + wm * 64 + i * 16 + lq * 4;  // + r
      const int bb = mbase >> 11;
      const int s0 = mbase & 2047;
#pragma unroll
      for (int j = 0; j < 4; ++j) {
        const int nb = n0 + wn * 64 + j * 16;
        const int tt = nb >> 9;
        const int hh = (nb >> 6) & 7;
        const int d0 = nb & 63;
        const int bh = bb * NHEAD + hh;
        if (tt == 2) {
          ushort4 pk;
          pk.x = f32_to_bf16_rn(acc[i][j][0]);
          pk.y = f32_to_bf16_rn(acc[i][j][1]);
          pk.z = f32_to_bf16_rn(acc[i][j][2]);
          pk.w = f32_to_bf16_rn(acc[i][j][3]);
          *(ushort4*)(vto + ((size_t)bh * HD + d0 + lr) * SEQ + s0) = pk;
        } else {
          ushort* dst = (tt == 0) ? qo : ko;
#pragma unroll
          for (int r = 0; r < 4; ++r)
            dst[((size_t)bh * SEQ + s0 + r) * HD + d0 + lr] = f32_to_bf16_rn(acc[i][j][r]);
        }
      }
    }
  } else {
#pragma unroll
    for (int i = 0; i < 4; ++i) {
#pragma unroll
      for (int j = 0; j < 4; ++j) {
        const int n = n0 + wn * 64 + j * 16 + lr;
        const float bv = bias[n];
#pragma unroll
        for (int r = 0; r < 4; ++r) {
          const int m = m0 + wm * 64 + i * 16 + lq * 4 + r;
          outf[(size_t)m * 512 + n] = acc[i][j][r] + bv;
        }
      }
    }
  }
}

// -------------------------------- fused flash attention ---------------------
// 1D grid of 1024 (XCD-swizzled: 8 h-blocks of a (b,qtile) share one XCD's L2
// for the mask slab). 128 threads = 2 waves; each wave owns 32 q-rows as two
// 16-row groups (A: w*32+0..15, B: +16). K/V tile 64 staged via named regs;
// K-frags and V-frags read once per wave, used by BOTH groups.
__global__ __launch_bounds__(128) void attn_fused(
    const ushort* __restrict__ Q, const ushort* __restrict__ Kt,
    const ushort* __restrict__ VT, const float* __restrict__ mask,
    const float* __restrict__ Btab, ushort* __restrict__ Out) {
  __shared__ ushort Ks[64 * 72];       //  9216 B
  __shared__ ushort Vs[64 * 72];       //  9216 B
  __shared__ ushort Ps[2][32 * 68];    //  8704 B (A rows 0-15, B rows 16-31)
  __shared__ ushort Bw[2112];          //  4224 B  bias*log2e, bf16
                                       // total 31360 B -> 5 blocks/CU

  const int flat = blockIdx.x;
  const int xcd = flat & 7;
  const int rr = flat >> 3;
  const int h = rr & 7;
  const int slot = rr >> 3;          // 0..15
  const int g = slot * 8 + xcd;      // 0..127  (b,qt) group
  const int qt = g & 31, b = g >> 5;

  const int bh = b * NHEAD + h;
  const ushort* qh = Q + (size_t)bh * SEQ * HD;
  const ushort* kh = Kt + (size_t)bh * SEQ * HD;
  const ushort* vh = VT + (size_t)bh * HD * SEQ;
  const float* mb = mask + (size_t)b * SEQ * SEQ;
  const float* bt = Btab + h * (2 * SEQ - 1);

  const int t = threadIdx.x;
  const int lane = t & 63, w = t >> 6;       // 2 waves
  const int lr = lane & 15, lq = lane >> 4;
  const int qb0 = qt * 64;
  const int qbaseA = qb0 + w * 32;           // group A rows
  const int qbaseB = qbaseA + 16;            // group B rows

  // stage bias window [qb0, qb0+2110] once, bf16, prescaled by log2(e)
  for (int i = t; i < 2111; i += 128)
    Bw[i] = f32_to_bf16_rn(bt[qb0 + i] * 1.44269504f);

  // Q fragments for both groups — loaded once
  short8 qfA0, qfA1, qfB0, qfB1;
  {
    const ushort* qpA = qh + (size_t)(qbaseA + lr) * HD + lq * 8;
    qfA0 = *(const short8*)qpA;
    qfA1 = *(const short8*)(qpA + 32);
    const ushort* qpB = qh + (size_t)(qbaseB + lr) * HD + lq * 8;
    qfB0 = *(const short8*)qpB;
    qfB1 = *(const short8*)(qpB + 32);
  }

  // mask base pointers (one per group; +r*SEQ added per access)
  const float* mpA = mb + (size_t)(qbaseA + lq * 4) * SEQ + lr;
  const float* mpB = mb + (size_t)(qbaseB + lq * 4) * SEQ + lr;

  float lA0 = 0.f, lA1 = 0.f, lA2 = 0.f, lA3 = 0.f;
  float lB0 = 0.f, lB1 = 0.f, lB2 = 0.f, lB3 = 0.f;
  f32x4 ofA[4], ofB[4];
#pragma unroll
  for (int i = 0; i < 4; ++i) {
    ofA[i] = (f32x4){0.f, 0.f, 0.f, 0.f};
    ofB[i] = (f32x4){0.f, 0.f, 0.f, 0.f};
  }

  const int qrlA = w * 32 + lq * 4;  // q-row (block-local) of group A (+r)
  const int srow = t >> 3;           // staging row 0..15 (+16p)
  const int sseg = t & 7;            // staging 16B segment

  // per-thread staging source bases (p-th chunk at +p*16 rows)
  const ushort* kp = kh + (size_t)srow * HD + sseg * 8;   // + kv0*HD + p*1024
  const ushort* vp = vh + (size_t)srow * SEQ + sseg * 8;  // + kv0 + p*16*SEQ

  // prologue: tile-0 K/V into named regs; tile-0 group-A mask prefetch
  uint4 kr0 = *(const uint4*)(kp);
  uint4 kr1 = *(const uint4*)(kp + 1024);
  uint4 kr2 = *(const uint4*)(kp + 2048);
  uint4 kr3 = *(const uint4*)(kp + 3072);
  uint4 vr0 = *(const uint4*)(vp);
  uint4 vr1 = *(const uint4*)(vp + 16 * SEQ);
  uint4 vr2 = *(const uint4*)(vp + 32 * SEQ);
  uint4 vr3 = *(const uint4*)(vp + 48 * SEQ);
  float mnA[4][4];
#pragma unroll
  for (int f = 0; f < 4; ++f)
#pragma unroll
    for (int r = 0; r < 4; ++r) mnA[f][r] = mpA[(size_t)r * SEQ + f * 16];

  for (int kv0 = 0; kv0 < SEQ; kv0 += 64) {
    __syncthreads();  // all waves done reading previous tile's Ks/Vs
    *(uint4*)&Ks[(srow)*72 + sseg * 8] = kr0;
    *(uint4*)&Ks[(16 + srow) * 72 + sseg * 8] = kr1;
    *(uint4*)&Ks[(32 + srow) * 72 + sseg * 8] = kr2;
    *(uint4*)&Ks[(48 + srow) * 72 + sseg * 8] = kr3;
    *(uint4*)&Vs[(srow)*72 + sseg * 8] = vr0;
    *(uint4*)&Vs[(16 + srow) * 72 + sseg * 8] = vr1;
    *(uint4*)&Vs[(32 + srow) * 72 + sseg * 8] = vr2;
    *(uint4*)&Vs[(48 + srow) * 72 + sseg * 8] = vr3;
    __syncthreads();  // Ks/Vs ready

    const int nkv = (kv0 + 64 < SEQ) ? (kv0 + 64) : 0;

    // group-B mask for THIS tile (consumed in SM_B, ~QK+SM_A later)
    float mnB[4][4];
#pragma unroll
    for (int f = 0; f < 4; ++f)
#pragma unroll
      for (int r = 0; r < 4; ++r) mnB[f][r] = mpB[(size_t)r * SEQ + kv0 + f * 16];

    // QK for BOTH groups — each K fragment read once
    f32x4 sfA[4], sfB[4];
#pragma unroll
    for (int f = 0; f < 4; ++f) {
      const ushort* kfp = &Ks[(f * 16 + lr) * 72 + lq * 8];
      const short8 k0 = *(const short8*)kfp;
      const short8 k1 = *(const short8*)(kfp + 32);
      sfA[f] = (f32x4){0.f, 0.f, 0.f, 0.f};
      sfA[f] = __builtin_amdgcn_mfma_f32_16x16x32_bf16(qfA0, k0, sfA[f], 0, 0, 0);
      sfA[f] = __builtin_amdgcn_mfma_f32_16x16x32_bf16(qfA1, k1, sfA[f], 0, 0, 0);
      sfB[f] = (f32x4){0.f, 0.f, 0.f, 0.f};
      sfB[f] = __builtin_amdgcn_mfma_f32_16x16x32_bf16(qfB0, k0, sfB[f], 0, 0, 0);
      sfB[f] = __builtin_amdgcn_mfma_f32_16x16x32_bf16(qfB1, k1, sfB[f], 0, 0, 0);
    }

    // SM_A: p = exp2(s*scale*log2e + bias*log2e + mask*log2e); rows 0..15
#pragma unroll
    for (int f = 0; f < 4; ++f) {
      const int ib = qrlA - (kv0 + f * 16 + lr) + 2047;  // + r
#pragma unroll
      for (int r = 0; r < 4; ++r) {
        const float bw = __builtin_bit_cast(float, ((unsigned)Bw[ib + r]) << 16);
        const float xs = fmaf(sfA[f][r], 0.18033688f,
                              fmaf(mnA[f][r], 1.44269504f, bw));
        const float p = __builtin_amdgcn_exp2f(xs);
        if (r == 0) lA0 += p; else if (r == 1) lA1 += p;
        else if (r == 2) lA2 += p; else lA3 += p;
        const unsigned u = __builtin_bit_cast(unsigned, p);
        Ps[w][(lq * 4 + r) * 68 + f * 16 + lr] =
            (unsigned short)((u + 0x8000u) >> 16);
      }
    }

    // group-A mask prefetch for NEXT tile (after last use of mnA)
#pragma unroll
    for (int f = 0; f < 4; ++f)
#pragma unroll
      for (int r = 0; r < 4; ++r) mnA[f][r] = mpA[(size_t)r * SEQ + nkv + f * 16];

    // SM_B: rows 16..31
#pragma unroll
    for (int f = 0; f < 4; ++f) {
      const int ib = qrlA + 16 - (kv0 + f * 16 + lr) + 2047;  // + r
#pragma unroll
      for (int r = 0; r < 4; ++r) {
        const float bw = __builtin_bit_cast(float, ((unsigned)Bw[ib + r]) << 16);
        const float xs = fmaf(sfB[f][r], 0.18033688f,
                              fmaf(mnB[f][r], 1.44269504f, bw));
        const float p = __builtin_amdgcn_exp2f(xs);
        if (r == 0) lB0 += p; else if (r == 1) lB1 += p;
        else if (r == 2) lB2 += p; else lB3 += p;
        const unsigned u = __builtin_bit_cast(unsigned, p);
        Ps[w][(16 + lq * 4 + r) * 68 + f * 16 + lr] =
            (unsigned short)((u + 0x8000u) >> 16);
      }
    }

    // next tile's K/V staging loads — latency hidden under PV
    kr0 = *(const uint4*)(kp + (size_t)nkv * HD);
    kr1 = *(const uint4*)(kp + (size_t)nkv * HD + 1024);
    kr2 = *(const uint4*)(kp + (size_t)nkv * HD + 2048);
    kr3 = *(const uint4*)(kp + (size_t)nkv * HD + 3072);
    vr0 = *(const uint4*)(vp + nkv);
    vr1 = *(const uint4*)(vp + nkv + 16 * SEQ);
    vr2 = *(const uint4*)(vp + nkv + 32 * SEQ);
    vr3 = *(const uint4*)(vp + nkv + 48 * SEQ);

    // PV for BOTH groups — each V fragment read once
#pragma unroll
    for (int ks = 0; ks < 2; ++ks) {
      union { uint2 u[2]; short8 s; } puA, puB;
      const int pbase = ks * 32 + lq * 8;
      puA.u[0] = *(const uint2*)&Ps[w][lr * 68 + pbase];
      puA.u[1] = *(const uint2*)&Ps[w][lr * 68 + pbase + 4];
      puB.u[0] = *(const uint2*)&Ps[w][(16 + lr) * 68 + pbase];
      puB.u[1] = *(const uint2*)&Ps[w][(16 + lr) * 68 + pbase + 4];
#pragma unroll
      for (int hf = 0; hf < 4; ++hf) {
        const short8 vf = *(const short8*)&Vs[(hf * 16 + lr) * 72 + ks * 32 + lq * 8];
        ofA[hf] = __builtin_amdgcn_mfma_f32_16x16x32_bf16(puA.s, vf, ofA[hf], 0, 0, 0);
        ofB[hf] = __builtin_amdgcn_mfma_f32_16x16x32_bf16(puB.s, vf, ofB[hf], 0, 0, 0);
      }
    }
  }

  // cross-lane l reductions (16-lane groups), normalize, write both groups
  float lA[4] = {lA0, lA1, lA2, lA3};
  float lB[4] = {lB0, lB1, lB2, lB3};
#pragma unroll
  for (int r = 0; r < 4; ++r) {
    float v = lA[r];
    v += __shfl_xor(v, 1); v += __shfl_xor(v, 2);
    v += __shfl_xor(v, 4); v += __shfl_xor(v, 8);
    lA[r] = v;
    float u = lB[r];
    u += __shfl_xor(u, 1); u += __shfl_xor(u, 2);
    u += __shfl_xor(u, 4); u += __shfl_xor(u, 8);
    lB[r] = u;
  }
#pragma unroll
  for (int r = 0; r < 4; ++r) {
    const float invA = 1.0f / lA[r];
    const int qrA = qbaseA + lq * 4 + r;
    ushort* opA = Out + ((size_t)(b * SEQ + qrA)) * CDIM + h * HD;
#pragma unroll
    for (int hf = 0; hf < 4; ++hf) opA[hf * 16 + lr] = f32_to_bf16_rn(ofA[hf][r] * invA);
    const float invB = 1.0f / lB[r];
    const int qrB = qbaseB + lq * 4 + r;
    ushort* opB = Out + ((size_t)(b * SEQ + qrB)) * CDIM + h * HD;
#pragma unroll
    for (int hf = 0; hf < 4; ++hf) opB[hf * 16 + lr] = f32_to_bf16_rn(ofB[hf][r] * invB);
  }
}

// ---------------------------------------------------------------------------
extern "C" void kernel_launch(void* const* d_in, const int* in_sizes, int n_in,
                              void* d_out, int out_size, void* d_ws, size_t ws_size,
                              hipStream_t stream) {
  const float* x     = (const float*)d_in[0];
  const float* mask  = (const float*)d_in[1];
  const float* Wqkv  = (const float*)d_in[2];
  const float* Btab  = (const float*)d_in[3];
  const float* Wproj = (const float*)d_in[4];
  const float* bproj = (const float*)d_in[5];
  float* out = (float*)d_out;

  char* ws = (char*)d_ws;
  const size_t SZ_X   = (size_t)NBATCH * SEQ * CDIM;
  const size_t SZ_QKV = (size_t)3 * CDIM * CDIM;
  const size_t SZ_PRJ = (size_t)CDIM * CDIM;
  const size_t SZ_HD  = (size_t)NBATCH * NHEAD * SEQ * HD;

  ushort* xb    = (ushort*)ws; ws += SZ_X * 2;
  ushort* wqkvb = (ushort*)ws; ws += SZ_QKV * 2;
  ushort* wprjb = (ushort*)ws; ws += SZ_PRJ * 2;
  ushort* qb    = (ushort*)ws; ws += SZ_HD * 2;
  ushort* kb    = (ushort*)ws; ws += SZ_HD * 2;
  ushort* vtb   = (ushort*)ws; ws += SZ_HD * 2;
  ushort* aob   = (ushort*)ws; ws += SZ_X * 2;

  {
    int n4 = (int)(SZ_X / 4);
    int g = (n4 + 255) / 256; if (g > 4096) g = 4096;
    cvt_f32_bf16<<<g, 256, 0, stream>>>(x, xb, n4);
  }
  {
    int n4 = (int)(SZ_QKV / 4);
    cvt_f32_bf16<<<(n4 + 255) / 256, 256, 0, stream>>>(Wqkv, wqkvb, n4);
  }
  {
    int n4 = (int)(SZ_PRJ / 4);
    cvt_f32_bf16<<<(n4 + 255) / 256, 256, 0, stream>>>(Wproj, wprjb, n4);
  }

  // QKV: M=8192, N=1536, K=512
  gemm_nt<0><<<dim3(12, 64), 256, 0, stream>>>(xb, wqkvb, qb, kb, vtb, nullptr, nullptr);

  // fused attention (1D swizzled grid, 128-thread blocks)
  attn_fused<<<dim3(1024), 128, 0, stream>>>(qb, kb, vtb, mask, Btab, aob);

  // proj: M=8192, N=512, K=512, +bias, f32 out
  gemm_nt<1><<<dim3(4, 64), 256, 0, stream>>>(aob, wprjb, nullptr, nullptr, nullptr, bproj, out);
}